// Round 6
// baseline (379.905 us; speedup 1.0000x reference)
//
#include <hip/hip_runtime.h>
#include <hip/hip_bf16.h>
#include <stdint.h>

typedef __bf16 bf16_t;
typedef __bf16 bf16x8 __attribute__((ext_vector_type(8)));
typedef __bf16 bf16x4 __attribute__((ext_vector_type(4)));
typedef float  f32x4  __attribute__((ext_vector_type(4)));

#define AS_GLOBAL __attribute__((address_space(1)))
#define AS_LDS    __attribute__((address_space(3)))
#define VMW(N) asm volatile("s_waitcnt vmcnt(" #N ")" ::: "memory")

static constexpr int CCH   = 256;
static constexpr int HP    = 34;
static constexpr int PLANE = HP * HP;   // 1156 padded pixels per image

// ---------------- BN parameter folding ----------------
__global__ void prep_params_k(const float* g1, const float* b1, const float* m1, const float* v1,
                              const float* g2, const float* b2, const float* m2, const float* v2,
                              float* prm) {
  int i = threadIdx.x;
  float i1 = g1[i] * rsqrtf(v1[i] + 1e-5f);
  prm[i]       = i1;
  prm[256 + i] = b1[i] - m1[i] * i1;
  float i2 = g2[i] * rsqrtf(v2[i] + 1e-5f);
  prm[512 + i] = i2;
  prm[768 + i] = b2[i] - m2[i] * i2;
}

// ---------------- masked weights -> bf16, [khw][co][ci] ----------------
__global__ __launch_bounds__(256) void prep_weights_k(const float* __restrict__ w,
                                                      const float* __restrict__ msk,
                                                      bf16_t* __restrict__ out) {
  int idx = blockIdx.x * 256 + threadIdx.x;
  const float* wp = w + (long)idx * 9;
  const float* mp = msk + (long)idx * 9;
#pragma unroll
  for (int khw = 0; khw < 9; ++khw)
    out[khw * 65536 + idx] = (bf16_t)(wp[khw] * mp[khw]);
}

// ---------------- zero only the pad borders of both intermediates ----------------
__global__ __launch_bounds__(256) void zero_borders_k(bf16_t* __restrict__ t0p,
                                                      bf16_t* __restrict__ t1p) {
  const int bid = blockIdx.x;               // 128: image n = bid>>1, buffer = bid&1
  bf16_t* base = ((bid & 1) ? t1p : t0p) + (long)(bid >> 1) * PLANE * CCH;
  for (int i = threadIdx.x; i < 132 * 32; i += 256) {
    int pix = i >> 5, c16 = i & 31;
    int r, col;
    if (pix < 34)       { r = 0;           col = pix; }
    else if (pix < 68)  { r = 33;          col = pix - 34; }
    else if (pix < 100) { r = pix - 68 + 1; col = 0; }
    else                { r = pix - 100 + 1; col = 33; }
    *(f32x4*)&base[(r * HP + col) * CCH + c16 * 8] = f32x4{0.f, 0.f, 0.f, 0.f};
  }
}

// ------- relu(bn1(x)) -> bf16, NCHW -> channels-last padded [n][34*34][256] -------
__global__ __launch_bounds__(256) void prep_input_k(const float* __restrict__ x,
                                                    const float* __restrict__ prm,
                                                    bf16_t* __restrict__ t0p) {
  __shared__ __align__(16) bf16_t tile[64 * 256];
  const int tid = threadIdx.x;
  const int bid = blockIdx.x;
  const int n   = bid >> 4;
  const int p0  = (bid & 15) << 6;
  const int px    = tid & 63;
  const int cbase = tid >> 6;
  for (int r = 0; r < 64; ++r) {
    int ci = r * 4 + cbase;
    float v = x[((n * 256 + ci) << 10) + p0 + px];
    float y = fmaxf(v * prm[ci] + prm[256 + ci], 0.f);
    int byte = px * 512 + ((ci * 2) ^ ((px & 7) << 4));
    *(bf16_t*)((char*)tile + byte) = (bf16_t)y;
  }
  __syncthreads();
  for (int j = 0; j < 8; ++j) {
    int off  = j * 256 + tid;
    int pix  = off >> 5;
    int c16  = off & 31;
    int byte = pix * 512 + ((c16 * 16) ^ ((pix & 7) << 4));
    bf16x8 v = *(const bf16x8*)((char*)tile + byte);
    int p = p0 + pix;
    long gp = ((long)n * PLANE + ((p >> 5) + 1) * HP + (p & 31) + 1) * CCH + c16 * 8;
    *(bf16x8*)(t0p + gp) = v;
  }
}

// ------- implicit-GEMM 3x3 conv: 4 waves x (128co x 128px), self-pipelined -------
// Block 256co x 256px, 256 threads, grid 256 = 1 block/CU, 1 wave/SIMD.
// 72 K-tiles (8 ci-chunks x 9 taps, K=32), 64 MFMA/tile/wave, acc[8][8].
// A [256co][32ci] triple-buffered, staged 2 tiles ahead; B patch [10r][34c][32ci]
// double-buffered per chunk (6 pieces over taps 1..6). Fragments double-buffered
// in registers: tile t issues the 16 ds_reads for t+1 (alt set), waits
// lgkmcnt(15) (own set complete), then runs 64 independent MFMA — LDS reads,
// staged loads and MFMA all overlap within the single wave's stream.
template <int EPI>
__global__ __launch_bounds__(256, 1) void conv3x3_k(const bf16_t* __restrict__ inp,
                                                    const bf16_t* __restrict__ wts,
                                                    const float* __restrict__ prm,
                                                    const float* __restrict__ resid,
                                                    bf16_t* __restrict__ out_cl,
                                                    float* __restrict__ out_f) {
  __shared__ __align__(128) bf16_t As[3][8192];    // 3 x 16 KB  [256co][32ci]
  __shared__ __align__(128) bf16_t Bs[2][12288];   // 2 x 24 KB  (1360 granules + slack)

  const int tid  = threadIdx.x;
  const int lane = tid & 63;
  const int wid  = tid >> 6;     // 0..3
  const int wm   = wid >> 1;     // co half (128)
  const int wn   = wid & 1;      // px half (128)

  const int bid = blockIdx.x;    // 256 = 64 n * 4 row-groups (1 block/CU)
  const int n   = bid >> 2;
  const int hb  = (bid & 3) << 3;  // padded top row of this block's 10-row patch

  const int swz8 = (((lane & 3) ^ ((lane >> 2) & 3) ^ (lane >> 4)) << 3);
  const int l15  = lane & 15;
  const int k4   = lane >> 4;

  // staging address helpers (derivations carried from verified R2-R4 machinery)
  const int rowq  = tid >> 2;
  const int aslot = (tid & 3) ^ ((tid >> 2) & 3) ^ ((tid >> 4) & 3);
  int bofs[6];
#pragma unroll
  for (int j = 0; j < 6; ++j) {
    int s = j * 256 + tid; if (s > 1359) s = 1359;
    int r = s / 136; int rem = s - r * 136; int cc = rem >> 2;
    int ks = ((rem & 3) - (cc >> 1)) & 3;   // inverse of read swizzle
    bofs[j] = (n * PLANE + (hb + r) * HP + cc) * CCH + (ks << 3);
  }

  f32x4 acc[8][8];
#pragma unroll
  for (int i = 0; i < 8; ++i)
#pragma unroll
    for (int j = 0; j < 8; ++j) acc[i][j] = f32x4{0.f, 0.f, 0.f, 0.f};

  bf16x8 avA[8], bvA[8], avB[8], bvB[8];   // two fragment sets (tile parity)

  auto stageA = [&](int abuf, int cw, int tw) {   // 4 loads/thread: 256co x 32ci
#pragma unroll
    for (int j = 0; j < 4; ++j) {
      const bf16_t* ga = wts + ((tw * CCH + j * 64 + rowq) * CCH + (cw << 5) + (aslot << 3));
      __builtin_amdgcn_global_load_lds((const AS_GLOBAL void*)ga,
                                       (AS_LDS void*)(&As[abuf][(j * 256 + tid) * 8]), 16, 0, 0);
    }
  };

#define STB(J, BBUF, CN) do {                                                        \
    const bf16_t* gb_ = inp + bofs[J] + ((CN) << 5);                                 \
    __builtin_amdgcn_global_load_lds((const AS_GLOBAL void*)gb_,                     \
        (AS_LDS void*)(&Bs[BBUF][((J) * 256 + tid) * 8]), 16, 0, 0);                 \
  } while (0)

#define PREF(AV, BV, AB, BB, KH, KW) do {                                            \
    _Pragma("unroll") for (int mi = 0; mi < 8; ++mi)                                 \
      AV[mi] = *(const bf16x8*)&As[AB][((wm * 128 + mi * 16 + l15) << 5) + swz8];    \
    _Pragma("unroll") for (int ni = 0; ni < 8; ++ni) {                               \
      const int p_    = (wn << 7) + (ni << 4) + l15;                                 \
      const int cc_   = (p_ & 31) + (KW);                                            \
      const int slot_ = ((p_ >> 5) + (KH)) * 136 + (cc_ << 2) + ((k4 + (cc_ >> 1)) & 3); \
      BV[ni] = *(const bf16x8*)&Bs[BB][slot_ << 3];                                  \
    }                                                                                \
  } while (0)

#define MFMA64(AV, BV) do {                                                          \
    _Pragma("unroll") for (int mi = 0; mi < 8; ++mi)                                 \
    _Pragma("unroll") for (int ni = 0; ni < 8; ++ni)                                 \
      acc[mi][ni] = __builtin_amdgcn_mfma_f32_16x16x32_bf16(AV[mi], BV[ni], acc[mi][ni], 0, 0, 0); \
  } while (0)

  // one K-tile. TAP/PAR/LASTC literal; c runtime. tile t = 9c+TAP, set=(PAR+TAP)&1.
#define TILE(TAP, PAR, LASTC) do {                                                   \
    __builtin_amdgcn_s_barrier();                                                    \
    if (!(LASTC) && (TAP) >= 1 && (TAP) <= 6) { STB((TAP) - 1, (PAR) ^ 1, c + 1); }  \
    if (!((LASTC) && (TAP) >= 7)) {                                                  \
      stageA(((TAP) + 2) % 3, ((TAP) <= 6) ? c : c + 1, ((TAP) + 2) % 9);            \
    }                                                                                \
    if (LASTC) { if ((TAP) <= 6) { VMW(4); } else { VMW(0); } }                      \
    else if ((TAP) >= 1 && (TAP) <= 6) { VMW(5); }                                   \
    else { VMW(4); }                                                                 \
    if (!((LASTC) && (TAP) == 8)) {                                                  \
      constexpr int T1  = ((TAP) + 1) % 9;                                           \
      constexpr int AB1 = ((TAP) + 1) % 3;                                           \
      constexpr int BB1 = ((TAP) < 8) ? (PAR) : ((PAR) ^ 1);                         \
      if (((PAR) + (TAP)) & 1) { PREF(avA, bvA, AB1, BB1, T1 / 3, T1 % 3); }         \
      else                     { PREF(avB, bvB, AB1, BB1, T1 / 3, T1 % 3); }         \
      asm volatile("s_waitcnt lgkmcnt(15)" ::: "memory");                            \
    } else {                                                                         \
      asm volatile("s_waitcnt lgkmcnt(0)" ::: "memory");                             \
    }                                                                                \
    __builtin_amdgcn_sched_barrier(0);                                               \
    if (((PAR) + (TAP)) & 1) { MFMA64(avB, bvB); } else { MFMA64(avA, bvA); }        \
  } while (0)

#define CH(PAR) do {                                                                 \
    TILE(0, PAR, 0); TILE(1, PAR, 0); TILE(2, PAR, 0); TILE(3, PAR, 0);              \
    TILE(4, PAR, 0); TILE(5, PAR, 0); TILE(6, PAR, 0); TILE(7, PAR, 0);              \
    TILE(8, PAR, 0);                                                                 \
  } while (0)

  // prologue: B(0) all 6 pieces, A(0), A(1); wait A(0); read frags(0) into set A
  STB(0, 0, 0); STB(1, 0, 0); STB(2, 0, 0); STB(3, 0, 0); STB(4, 0, 0); STB(5, 0, 0);
  stageA(0, 0, 0);
  stageA(1, 0, 1);
  VMW(4);
  __builtin_amdgcn_s_barrier();
  PREF(avA, bvA, 0, 0, 0, 0);

  int c = 0;
#pragma unroll 1
  for (int it = 0; it < 3; ++it) {
    CH(0); ++c;
    CH(1); ++c;
  }
  CH(0); ++c;                      // c = 6
  // tail chunk c = 7 (PAR = 1)
  TILE(0, 1, 1); TILE(1, 1, 1); TILE(2, 1, 1); TILE(3, 1, 1); TILE(4, 1, 1);
  TILE(5, 1, 1); TILE(6, 1, 1); TILE(7, 1, 1); TILE(8, 1, 1);

#undef TILE
#undef CH
#undef PREF
#undef MFMA64
#undef STB

  // C/D layout: col(pixel) = lane&15, row(co) = (lane>>4)*4 + reg
  if (EPI == 0) {
#pragma unroll
    for (int mi = 0; mi < 8; ++mi) {
      const int co_b = wm * 128 + mi * 16 + ((lane >> 4) << 2);
      const float s0 = prm[co_b], s1 = prm[co_b + 1], s2 = prm[co_b + 2], s3 = prm[co_b + 3];
      const float t0 = prm[256 + co_b], t1 = prm[256 + co_b + 1],
                  t2 = prm[256 + co_b + 2], t3 = prm[256 + co_b + 3];
#pragma unroll
      for (int ni = 0; ni < 8; ++ni) {
        f32x4 v = acc[mi][ni];
        const int p  = (wn << 7) + (ni << 4) + l15;
        const int pr = p >> 5, pc = p & 31;
        bf16x4 pk;
        pk[0] = (bf16_t)fmaxf(v[0] * s0 + t0, 0.f);
        pk[1] = (bf16_t)fmaxf(v[1] * s1 + t1, 0.f);
        pk[2] = (bf16_t)fmaxf(v[2] * s2 + t2, 0.f);
        pk[3] = (bf16_t)fmaxf(v[3] * s3 + t3, 0.f);
        *(bf16x4*)&out_cl[(n * PLANE + (hb + pr + 1) * HP + pc + 1) * CCH + co_b] = pk;
      }
    }
  } else {
#pragma unroll
    for (int mi = 0; mi < 8; ++mi) {
      const int co_b = wm * 128 + mi * 16 + ((lane >> 4) << 2);
#pragma unroll
      for (int ni = 0; ni < 8; ++ni) {
        f32x4 v = acc[mi][ni];
        const int p  = (wn << 7) + (ni << 4) + l15;
        const int gp = ((n * CCH + co_b) << 10) + (hb << 5) + p;
        out_f[gp]        = v[0] + resid[gp];
        out_f[gp + 1024] = v[1] + resid[gp + 1024];
        out_f[gp + 2048] = v[2] + resid[gp + 2048];
        out_f[gp + 3072] = v[3] + resid[gp + 3072];
      }
    }
  }
}

extern "C" void kernel_launch(void* const* d_in, const int* in_sizes, int n_in,
                              void* d_out, int out_size, void* d_ws, size_t ws_size,
                              hipStream_t stream) {
  const float* x  = (const float*)d_in[0];
  const float* g1 = (const float*)d_in[1];
  const float* b1 = (const float*)d_in[2];
  const float* m1 = (const float*)d_in[3];
  const float* v1 = (const float*)d_in[4];
  const float* w1 = (const float*)d_in[5];
  const float* k1 = (const float*)d_in[6];
  const float* g2 = (const float*)d_in[7];
  const float* b2 = (const float*)d_in[8];
  const float* m2 = (const float*)d_in[9];
  const float* v2 = (const float*)d_in[10];
  const float* w2 = (const float*)d_in[11];
  const float* k2 = (const float*)d_in[12];

  char* ws = (char*)d_ws;
  const size_t T0P_B = (size_t)64 * PLANE * CCH * 2;
  bf16_t* t0p = (bf16_t*)ws;
  bf16_t* t1p = (bf16_t*)(ws + T0P_B);
  bf16_t* mw1 = (bf16_t*)(ws + 2 * T0P_B);
  bf16_t* mw2 = (bf16_t*)(ws + 2 * T0P_B + 1179648);
  float*  prm = (float*)(ws + 2 * T0P_B + 2 * 1179648);

  prep_params_k<<<1, 256, 0, stream>>>(g1, b1, m1, v1, g2, b2, m2, v2, prm);
  zero_borders_k<<<128, 256, 0, stream>>>(t0p, t1p);
  prep_weights_k<<<256, 256, 0, stream>>>(w1, k1, mw1);
  prep_weights_k<<<256, 256, 0, stream>>>(w2, k2, mw2);
  prep_input_k<<<1024, 256, 0, stream>>>(x, prm, t0p);

  conv3x3_k<0><<<256, 256, 0, stream>>>(t0p, mw1, prm + 512, nullptr, t1p, nullptr);
  conv3x3_k<1><<<256, 256, 0, stream>>>(t1p, mw2, nullptr, x, nullptr, (float*)d_out);
}

// Round 8
// 266.940 us; speedup vs baseline: 1.4232x; 1.4232x over previous
//
#include <hip/hip_runtime.h>
#include <hip/hip_bf16.h>
#include <stdint.h>

typedef __bf16 bf16_t;
typedef __bf16 bf16x8 __attribute__((ext_vector_type(8)));
typedef __bf16 bf16x4 __attribute__((ext_vector_type(4)));
typedef float  f32x4  __attribute__((ext_vector_type(4)));

#define AS_GLOBAL __attribute__((address_space(1)))
#define AS_LDS    __attribute__((address_space(3)))
#define VMW(N) asm volatile("s_waitcnt vmcnt(" #N ")" ::: "memory")
#define LGKM0()  asm volatile("s_waitcnt lgkmcnt(0)" ::: "memory")

static constexpr int CCH   = 256;
static constexpr int HP    = 34;
static constexpr int PLANE = HP * HP;   // 1156 padded pixels per image

// ---------------- BN parameter folding ----------------
__global__ void prep_params_k(const float* g1, const float* b1, const float* m1, const float* v1,
                              const float* g2, const float* b2, const float* m2, const float* v2,
                              float* prm) {
  int i = threadIdx.x;
  float i1 = g1[i] * rsqrtf(v1[i] + 1e-5f);
  prm[i]       = i1;
  prm[256 + i] = b1[i] - m1[i] * i1;
  float i2 = g2[i] * rsqrtf(v2[i] + 1e-5f);
  prm[512 + i] = i2;
  prm[768 + i] = b2[i] - m2[i] * i2;
}

// ---------------- masked weights -> bf16, [khw][co][ci] ----------------
__global__ __launch_bounds__(256) void prep_weights_k(const float* __restrict__ w,
                                                      const float* __restrict__ msk,
                                                      bf16_t* __restrict__ out) {
  int idx = blockIdx.x * 256 + threadIdx.x;
  const float* wp = w + (long)idx * 9;
  const float* mp = msk + (long)idx * 9;
#pragma unroll
  for (int khw = 0; khw < 9; ++khw)
    out[khw * 65536 + idx] = (bf16_t)(wp[khw] * mp[khw]);
}

// ---------------- zero only the pad borders of both intermediates ----------------
__global__ __launch_bounds__(256) void zero_borders_k(bf16_t* __restrict__ t0p,
                                                      bf16_t* __restrict__ t1p) {
  const int bid = blockIdx.x;               // 128: image n = bid>>1, buffer = bid&1
  bf16_t* base = ((bid & 1) ? t1p : t0p) + (long)(bid >> 1) * PLANE * CCH;
  for (int i = threadIdx.x; i < 132 * 32; i += 256) {
    int pix = i >> 5, c16 = i & 31;
    int r, col;
    if (pix < 34)       { r = 0;           col = pix; }
    else if (pix < 68)  { r = 33;          col = pix - 34; }
    else if (pix < 100) { r = pix - 68 + 1; col = 0; }
    else                { r = pix - 100 + 1; col = 33; }
    *(f32x4*)&base[(r * HP + col) * CCH + c16 * 8] = f32x4{0.f, 0.f, 0.f, 0.f};
  }
}

// ------- relu(bn1(x)) -> bf16, NCHW -> channels-last padded [n][34*34][256] -------
__global__ __launch_bounds__(256) void prep_input_k(const float* __restrict__ x,
                                                    const float* __restrict__ prm,
                                                    bf16_t* __restrict__ t0p) {
  __shared__ __align__(16) bf16_t tile[64 * 256];
  const int tid = threadIdx.x;
  const int bid = blockIdx.x;
  const int n   = bid >> 4;
  const int p0  = (bid & 15) << 6;
  const int px    = tid & 63;
  const int cbase = tid >> 6;
  for (int r = 0; r < 64; ++r) {
    int ci = r * 4 + cbase;
    float v = x[((n * 256 + ci) << 10) + p0 + px];
    float y = fmaxf(v * prm[ci] + prm[256 + ci], 0.f);
    int byte = px * 512 + ((ci * 2) ^ ((px & 7) << 4));
    *(bf16_t*)((char*)tile + byte) = (bf16_t)y;
  }
  __syncthreads();
  for (int j = 0; j < 8; ++j) {
    int off  = j * 256 + tid;
    int pix  = off >> 5;
    int c16  = off & 31;
    int byte = pix * 512 + ((c16 * 16) ^ ((pix & 7) << 4));
    bf16x8 v = *(const bf16x8*)((char*)tile + byte);
    int p = p0 + pix;
    long gp = ((long)n * PLANE + ((p >> 5) + 1) * HP + (p & 31) + 1) * CCH + c16 * 8;
    *(bf16x8*)(t0p + gp) = v;
  }
}

// ------------- implicit-GEMM 3x3 conv: m201-cadence 8-phase template -------------
// Block 256co x 256px, 8 waves (2M x 4N), wave 128co x 64px. K-step = 64
// (tap x ci-64), 36 steps, 4 phases/step. A dbuf 2x32KB staged 1 step ahead
// (quarter/phase); B patch [kf][10r][34c][32ci] dbuf staged >=3 steps ahead.
// FIX vs R6: Bs per-buffer padded 2720 -> 2784 granules. global_load_lds writes
// to firstlane-base + lane*16 (clamping per-lane sh only fixes the SOURCE), so
// the tail piece's linear dest runs to granule 2782; the pad region absorbs it
// (never read). Previously those writes corrupted Bs[1]'s head / past-LDS.
template <int EPI>
__global__ __launch_bounds__(512, 1) void conv3x3_k(const bf16_t* __restrict__ inp,
                                                    const bf16_t* __restrict__ wts,
                                                    const float* __restrict__ prm,
                                                    const float* __restrict__ resid,
                                                    bf16_t* __restrict__ out_cl,
                                                    float* __restrict__ out_f) {
  __shared__ __align__(128) bf16_t As[2][16384];   // 2 x 32 KB [256co][64ci] swizzled
  __shared__ __align__(128) bf16_t Bs[2][22272];   // 2 x (2720 real + 64 pad) granules

  const int tid  = threadIdx.x;
  const int lane = tid & 63;
  const int wid  = tid >> 6;     // 0..7
  const int wm   = wid >> 2;     // co half (128)
  const int wn   = wid & 3;      // px quarter (64)

  const int bid = blockIdx.x;    // 256 = 8 XCD x 32
  const int w   = ((bid & 7) << 5) + (bid >> 3);
  const int n   = w >> 2;
  const int hb  = (w & 3) << 3;  // padded top row of this block's 10-row patch

  const int l15 = lane & 15;
  const int k4  = lane >> 4;
  const int qe  = k4 ^ (lane & 3) ^ ((lane >> 2) & 3);  // A read slot (lane part)
  const int h1  = (lane >> 1) & 1;                      // A kf-half row swizzle

  f32x4 acc[8][4];
#pragma unroll
  for (int i = 0; i < 8; ++i)
#pragma unroll
    for (int j = 0; j < 4; ++j) acc[i][j] = f32x4{0.f, 0.f, 0.f, 0.f};

  bf16x8 av[4], bv[4];

  // stage one 64-co quarter of A(step): 1 load/thread, inverse-swizzled source
  auto stageAq = [&](int abuf, int c1, int t1, int q) {
    const int g   = q * 512 + tid;                 // granule
    const int co  = g >> 3;
    const int ps  = tid & 7;
    const int kfs = (ps >> 2) ^ ((tid >> 4) & 1);
    const int qq  = (ps & 3) ^ ((tid >> 3) & 3) ^ (((q << 4) + (tid >> 5)) & 3);
    const bf16_t* ga = wts + ((t1 * CCH + co) * CCH + (c1 << 6) + (kfs << 5) + (qq << 3));
    __builtin_amdgcn_global_load_lds((const AS_GLOBAL void*)ga,
                                     (AS_LDS void*)(&As[abuf][g * 8]), 16, 0, 0);
  };

  // stage one of 6 pieces of the B patch for chunk c1: 1 load/thread
  auto stageBp = [&](int bbuf, int c1, int J) {
    int sh = J * 512 + tid;
    if (sh > 2719) sh = 2719;                      // source clamp; dest overflow -> pad
    const int kfh = (sh >= 1360) ? 1 : 0;
    const int idx = sh - kfh * 1360;
    const int r   = idx / 136;
    const int rem = idx - r * 136;
    const int cc  = rem >> 2;
    const int ks  = ((rem & 3) - (cc >> 1)) & 3;   // inverse of read swizzle
    const bf16_t* gb = inp + ((n * PLANE + (hb + r) * HP + cc) * CCH
                              + (c1 << 6) + (kfh << 5) + (ks << 3));
    __builtin_amdgcn_global_load_lds((const AS_GLOBAL void*)gb,
                                     (AS_LDS void*)(&Bs[bbuf][sh * 8]), 16, 0, 0);
  };

#define LDA(AB, MH, KF) do {                                                         \
    _Pragma("unroll") for (int mi = 0; mi < 4; ++mi) {                               \
      const int r_ = wm * 128 + (MH) * 64 + mi * 16 + l15;                           \
      av[mi] = *(const bf16x8*)&As[AB][(r_ << 6) + (((KF) ^ h1) << 5) + (qe << 3)];  \
    }                                                                                \
  } while (0)

#define LDB(BB, TAP, KF) do {                                                        \
    constexpr int KH = (TAP) / 3, KW = (TAP) % 3;                                    \
    _Pragma("unroll") for (int ni = 0; ni < 4; ++ni) {                               \
      const int p_    = (wn << 6) + (ni << 4) + l15;                                 \
      const int cc_   = (p_ & 31) + KW;                                              \
      const int slot_ = ((p_ >> 5) + KH) * 136 + (cc_ << 2) + ((k4 + (cc_ >> 1)) & 3); \
      bv[ni] = *(const bf16x8*)&Bs[BB][(KF) * 10880 + slot_ * 8];                    \
    }                                                                                \
  } while (0)

#define MFMA16(MH) do {                                                              \
    _Pragma("unroll") for (int mi = 0; mi < 4; ++mi)                                 \
    _Pragma("unroll") for (int ni = 0; ni < 4; ++ni)                                 \
      acc[(MH) * 4 + mi][ni] =                                                       \
        __builtin_amdgcn_mfma_f32_16x16x32_bf16(av[mi], bv[ni], acc[(MH)*4+mi][ni], 0, 0, 0); \
  } while (0)

#define MMA_BLK(MH) do {                                                             \
    __builtin_amdgcn_s_barrier();                                                    \
    LGKM0();                                                                         \
    __builtin_amdgcn_sched_barrier(0);                                               \
    __builtin_amdgcn_s_setprio(1); MFMA16(MH); __builtin_amdgcn_s_setprio(0);        \
    __builtin_amdgcn_s_barrier();                                                    \
  } while (0)

  // one K-step (tap TAP of chunk c). Stages A(step+1) quarters in order 0,2,1,3.
#define STEP(TAP, LASTC) do {                                                        \
    const int ab = (c + (TAP)) & 1;                                                  \
    const int bb = c & 1;                                                            \
    constexpr int TN = ((TAP) + 1) % 9;                                              \
    const int cN = c + ((TAP) == 8);                                                 \
    /* ph0: (mh0, kf0) */                                                            \
    LDA(ab, 0, 0); LDB(bb, TAP, 0);                                                  \
    if (!((LASTC) && (TAP) == 8)) stageAq(ab ^ 1, cN, TN, 0);                        \
    if ((TAP) >= 1 && (TAP) <= 6 && !(LASTC)) { VMW(2); }                            \
    else if ((LASTC) && (TAP) == 8) { VMW(0); }                                      \
    else { VMW(1); }                                                                 \
    MMA_BLK(0);                                                                      \
    /* ph1: (mh1, kf0) */                                                            \
    LDA(ab, 1, 0);                                                                   \
    if (!((LASTC) && (TAP) == 8)) stageAq(ab ^ 1, cN, TN, 2);                        \
    MMA_BLK(1);                                                                      \
    /* ph2: (mh0, kf1) */                                                            \
    LDA(ab, 0, 1); LDB(bb, TAP, 1);                                                  \
    if (!((LASTC) && (TAP) == 8)) stageAq(ab ^ 1, cN, TN, 1);                        \
    MMA_BLK(0);                                                                      \
    /* ph3: (mh1, kf1) */                                                            \
    LDA(ab, 1, 1);                                                                   \
    if (!((LASTC) && (TAP) == 8)) stageAq(ab ^ 1, cN, TN, 3);                        \
    if (!(LASTC) && (TAP) <= 5) stageBp(bb ^ 1, c + 1, TAP);                         \
    if (!((LASTC) && (TAP) == 8)) {                                                  \
      if (!(LASTC) && (TAP) <= 5) { VMW(3); } else { VMW(2); }                       \
    }                                                                                \
    MMA_BLK(1);                                                                      \
  } while (0)

  // prologue: B(0) 6 pieces + A(0) quarters (order 0,2,1,3)
  stageBp(0, 0, 0); stageBp(0, 0, 1); stageBp(0, 0, 2);
  stageBp(0, 0, 3); stageBp(0, 0, 4); stageBp(0, 0, 5);
  stageAq(0, 0, 0, 0); stageAq(0, 0, 0, 2); stageAq(0, 0, 0, 1); stageAq(0, 0, 0, 3);
  VMW(2);                                   // q0,q2 + B done; q1,q3 in flight
  __builtin_amdgcn_s_barrier();

  int c = 0;
#pragma unroll 1
  for (; c < 3; ++c) {
    STEP(0, 0); STEP(1, 0); STEP(2, 0); STEP(3, 0); STEP(4, 0);
    STEP(5, 0); STEP(6, 0); STEP(7, 0); STEP(8, 0);
  }
  // tail chunk c == 3
  STEP(0, 1); STEP(1, 1); STEP(2, 1); STEP(3, 1); STEP(4, 1);
  STEP(5, 1); STEP(6, 1); STEP(7, 1); STEP(8, 1);

#undef STEP
#undef MMA_BLK
#undef MFMA16
#undef LDB
#undef LDA

  // C/D layout: col(pixel) = lane&15, row(co) = (lane>>4)*4 + reg
  if (EPI == 0) {
#pragma unroll
    for (int m = 0; m < 8; ++m) {
      const int co_b = wm * 128 + (m >> 2) * 64 + (m & 3) * 16 + ((lane >> 4) << 2);
      const float s0 = prm[co_b], s1 = prm[co_b + 1], s2 = prm[co_b + 2], s3 = prm[co_b + 3];
      const float t0 = prm[256 + co_b], t1 = prm[256 + co_b + 1],
                  t2 = prm[256 + co_b + 2], t3 = prm[256 + co_b + 3];
#pragma unroll
      for (int ni = 0; ni < 4; ++ni) {
        f32x4 v = acc[m][ni];
        const int p  = (wn << 6) + (ni << 4) + l15;
        const int pr = p >> 5, pc = p & 31;
        bf16x4 pk;
        pk[0] = (bf16_t)fmaxf(v[0] * s0 + t0, 0.f);
        pk[1] = (bf16_t)fmaxf(v[1] * s1 + t1, 0.f);
        pk[2] = (bf16_t)fmaxf(v[2] * s2 + t2, 0.f);
        pk[3] = (bf16_t)fmaxf(v[3] * s3 + t3, 0.f);
        *(bf16x4*)&out_cl[(n * PLANE + (hb + pr + 1) * HP + pc + 1) * CCH + co_b] = pk;
      }
    }
  } else {
#pragma unroll
    for (int m = 0; m < 8; ++m) {
      const int co_b = wm * 128 + (m >> 2) * 64 + (m & 3) * 16 + ((lane >> 4) << 2);
#pragma unroll
      for (int ni = 0; ni < 4; ++ni) {
        f32x4 v = acc[m][ni];
        const int p  = (wn << 6) + (ni << 4) + l15;
        const int gp = ((n * CCH + co_b) << 10) + (hb << 5) + p;
        out_f[gp]        = v[0] + resid[gp];
        out_f[gp + 1024] = v[1] + resid[gp + 1024];
        out_f[gp + 2048] = v[2] + resid[gp + 2048];
        out_f[gp + 3072] = v[3] + resid[gp + 3072];
      }
    }
  }
}

extern "C" void kernel_launch(void* const* d_in, const int* in_sizes, int n_in,
                              void* d_out, int out_size, void* d_ws, size_t ws_size,
                              hipStream_t stream) {
  const float* x  = (const float*)d_in[0];
  const float* g1 = (const float*)d_in[1];
  const float* b1 = (const float*)d_in[2];
  const float* m1 = (const float*)d_in[3];
  const float* v1 = (const float*)d_in[4];
  const float* w1 = (const float*)d_in[5];
  const float* k1 = (const float*)d_in[6];
  const float* g2 = (const float*)d_in[7];
  const float* b2 = (const float*)d_in[8];
  const float* m2 = (const float*)d_in[9];
  const float* v2 = (const float*)d_in[10];
  const float* w2 = (const float*)d_in[11];
  const float* k2 = (const float*)d_in[12];

  char* ws = (char*)d_ws;
  const size_t T0P_B = (size_t)64 * PLANE * CCH * 2;
  bf16_t* t0p = (bf16_t*)ws;
  bf16_t* t1p = (bf16_t*)(ws + T0P_B);
  bf16_t* mw1 = (bf16_t*)(ws + 2 * T0P_B);
  bf16_t* mw2 = (bf16_t*)(ws + 2 * T0P_B + 1179648);
  float*  prm = (float*)(ws + 2 * T0P_B + 2 * 1179648);

  prep_params_k<<<1, 256, 0, stream>>>(g1, b1, m1, v1, g2, b2, m2, v2, prm);
  zero_borders_k<<<128, 256, 0, stream>>>(t0p, t1p);
  prep_weights_k<<<256, 256, 0, stream>>>(w1, k1, mw1);
  prep_weights_k<<<256, 256, 0, stream>>>(w2, k2, mw2);
  prep_input_k<<<1024, 256, 0, stream>>>(x, prm, t0p);

  conv3x3_k<0><<<256, 512, 0, stream>>>(t0p, mw1, prm + 512, nullptr, t1p, nullptr);
  conv3x3_k<1><<<256, 512, 0, stream>>>(t1p, mw2, nullptr, x, nullptr, (float*)d_out);
}

// Round 9
// 225.474 us; speedup vs baseline: 1.6849x; 1.1839x over previous
//
#include <hip/hip_runtime.h>
#include <hip/hip_bf16.h>
#include <stdint.h>

typedef __bf16 bf16_t;
typedef __bf16 bf16x8 __attribute__((ext_vector_type(8)));
typedef __bf16 bf16x4 __attribute__((ext_vector_type(4)));
typedef float  f32x4  __attribute__((ext_vector_type(4)));

#define AS_GLOBAL __attribute__((address_space(1)))
#define AS_LDS    __attribute__((address_space(3)))
#define VMW(N) asm volatile("s_waitcnt vmcnt(" #N ")" ::: "memory")

static constexpr int CCH   = 256;
static constexpr int HP    = 34;
static constexpr int PLANE = HP * HP;   // 1156 padded pixels per image

// ---------------- BN parameter folding ----------------
__global__ void prep_params_k(const float* g1, const float* b1, const float* m1, const float* v1,
                              const float* g2, const float* b2, const float* m2, const float* v2,
                              float* prm) {
  int i = threadIdx.x;
  float i1 = g1[i] * rsqrtf(v1[i] + 1e-5f);
  prm[i]       = i1;
  prm[256 + i] = b1[i] - m1[i] * i1;
  float i2 = g2[i] * rsqrtf(v2[i] + 1e-5f);
  prm[512 + i] = i2;
  prm[768 + i] = b2[i] - m2[i] * i2;
}

// ---------------- masked weights -> bf16, [khw][co][ci] ----------------
__global__ __launch_bounds__(256) void prep_weights_k(const float* __restrict__ w,
                                                      const float* __restrict__ msk,
                                                      bf16_t* __restrict__ out) {
  int idx = blockIdx.x * 256 + threadIdx.x;
  const float* wp = w + (long)idx * 9;
  const float* mp = msk + (long)idx * 9;
#pragma unroll
  for (int khw = 0; khw < 9; ++khw)
    out[khw * 65536 + idx] = (bf16_t)(wp[khw] * mp[khw]);
}

// ---------------- zero only the pad borders of both intermediates ----------------
__global__ __launch_bounds__(256) void zero_borders_k(bf16_t* __restrict__ t0p,
                                                      bf16_t* __restrict__ t1p) {
  const int bid = blockIdx.x;               // 128: image n = bid>>1, buffer = bid&1
  bf16_t* base = ((bid & 1) ? t1p : t0p) + (long)(bid >> 1) * PLANE * CCH;
  for (int i = threadIdx.x; i < 132 * 32; i += 256) {
    int pix = i >> 5, c16 = i & 31;
    int r, col;
    if (pix < 34)       { r = 0;           col = pix; }
    else if (pix < 68)  { r = 33;          col = pix - 34; }
    else if (pix < 100) { r = pix - 68 + 1; col = 0; }
    else                { r = pix - 100 + 1; col = 33; }
    *(f32x4*)&base[(r * HP + col) * CCH + c16 * 8] = f32x4{0.f, 0.f, 0.f, 0.f};
  }
}

// ------- relu(bn1(x)) -> bf16, NCHW -> channels-last padded [n][34*34][256] -------
__global__ __launch_bounds__(256) void prep_input_k(const float* __restrict__ x,
                                                    const float* __restrict__ prm,
                                                    bf16_t* __restrict__ t0p) {
  __shared__ __align__(16) bf16_t tile[64 * 256];
  const int tid = threadIdx.x;
  const int bid = blockIdx.x;
  const int n   = bid >> 4;
  const int p0  = (bid & 15) << 6;
  const int px    = tid & 63;
  const int cbase = tid >> 6;
  for (int r = 0; r < 64; ++r) {
    int ci = r * 4 + cbase;
    float v = x[((n * 256 + ci) << 10) + p0 + px];
    float y = fmaxf(v * prm[ci] + prm[256 + ci], 0.f);
    int byte = px * 512 + ((ci * 2) ^ ((px & 7) << 4));
    *(bf16_t*)((char*)tile + byte) = (bf16_t)y;
  }
  __syncthreads();
  for (int j = 0; j < 8; ++j) {
    int off  = j * 256 + tid;
    int pix  = off >> 5;
    int c16  = off & 31;
    int byte = pix * 512 + ((c16 * 16) ^ ((pix & 7) << 4));
    bf16x8 v = *(const bf16x8*)((char*)tile + byte);
    int p = p0 + pix;
    long gp = ((long)n * PLANE + ((p >> 5) + 1) * HP + (p & 31) + 1) * CCH + c16 * 8;
    *(bf16x8*)(t0p + gp) = v;
  }
}

// -------- implicit-GEMM 3x3 conv: tap reuse, slim LDS, 3 blocks/CU ---------------
// 72 phases = 8 ci-chunks x 9 taps, K=32 each, 16 MFMA/wave/phase. A [128co][32ci]
// double-buffered (staged 1 phase ahead); B patch [6r][34c][32ci] double-buffered
// per ci-chunk (staged 9 phases ahead at t==0). LDS = 48 KB -> 3 blocks/CU:
// cross-block wave diversity hides each block's barrier/load stalls (m114 model).
// vmcnt (uniform per wave): wait A(p) -> younger = B(c+1)'s 4 loads iff t==1 and
// not last chunk, else 0.
template <int EPI>
__global__ __launch_bounds__(256, 3) void conv3x3_k(const bf16_t* __restrict__ inp,
                                                    const bf16_t* __restrict__ wts,
                                                    const float* __restrict__ prm,
                                                    const float* __restrict__ resid,
                                                    bf16_t* __restrict__ out_cl,
                                                    float* __restrict__ out_f) {
  __shared__ __align__(128) bf16_t As[2][4096];   // 2 x 8 KB weight tiles [co128][ci32]
  __shared__ __align__(128) bf16_t Bs[2][8192];   // 2 x 16 KB pixel patches (1024 granules)

  const int tid  = threadIdx.x;
  const int lane = tid & 63;
  const int wid  = tid >> 6;
  const int wm   = wid >> 1;
  const int wn   = wid & 1;

  const int bid = blockIdx.x;                  // 1024 = 8 XCDs * 128
  const int w   = ((bid & 7) << 7) + (bid >> 3);
  const int co0 = (w & 1) << 7;
  const int pt  = w >> 1;                      // 512 pixel tiles
  const int n   = pt >> 3;
  const int hb  = (pt & 7) << 2;               // padded input rows hb..hb+5 staged

  const int swz8 = (((lane & 3) ^ ((lane >> 2) & 3) ^ (lane >> 4)) << 3);
  const int l15  = lane & 15;
  const int k4   = lane >> 4;

  f32x4 acc[4][4];
#pragma unroll
  for (int i = 0; i < 4; ++i)
#pragma unroll
    for (int j = 0; j < 4; ++j) acc[i][j] = f32x4{0.f, 0.f, 0.f, 0.f};

  auto stageA = [&](int abuf, int c, int t) {   // 2 loads/thread
    const int ci0 = c << 5;
#pragma unroll
    for (int j = 0; j < 2; ++j) {
      const int ch  = wid * 2 + j;
      const int row = ch * 16 + (lane >> 2);
      const bf16_t* ga = wts + ((t * CCH + co0 + row) * CCH + ci0 + swz8);
      __builtin_amdgcn_global_load_lds((const AS_GLOBAL void*)ga,
                                       (AS_LDS void*)(&As[abuf][ch * 512]), 16, 0, 0);
    }
  };

  auto stageB = [&](int bbuf, int c) {          // 4 loads/thread (uniform per wave)
    const int ci0 = c << 5;
#pragma unroll
    for (int j = 0; j < 4; ++j) {
      const int ibase = wid * 4 + j;
      int s = (ibase << 6) + lane;
      if (s > 815) s = 815;                     // source clamp; dest tail -> slack
      const int r     = s / 136;
      const int rem   = s - r * 136;
      const int cc    = rem >> 2;
      const int k     = ((rem & 3) - (cc >> 1)) & 3;  // inverse of read swizzle
      const bf16_t* gb = inp + ((n * PLANE + (hb + r) * HP + cc) * CCH + ci0 + (k << 3));
      __builtin_amdgcn_global_load_lds((const AS_GLOBAL void*)gb,
                                       (AS_LDS void*)(&Bs[bbuf][ibase * 512]), 16, 0, 0);
    }
  };

  auto compute = [&](int ab, int bb, int kh, int kw) {
    bf16x8 av[4], bv[4];
#pragma unroll
    for (int mi = 0; mi < 4; ++mi)
      av[mi] = *(const bf16x8*)&As[ab][((wm * 64 + mi * 16 + l15) << 5) + swz8];
#pragma unroll
    for (int ni = 0; ni < 4; ++ni) {
      const int p    = (wn << 6) + (ni << 4) + l15;
      const int cc   = (p & 31) + kw;
      const int slot = ((p >> 5) + kh) * 136 + (cc << 2) + ((k4 + (cc >> 1)) & 3);
      bv[ni] = *(const bf16x8*)&Bs[bb][slot << 3];
    }
    __builtin_amdgcn_s_setprio(1);
#pragma unroll
    for (int mi = 0; mi < 4; ++mi)
#pragma unroll
      for (int ni = 0; ni < 4; ++ni)
        acc[mi][ni] = __builtin_amdgcn_mfma_f32_16x16x32_bf16(av[mi], bv[ni], acc[mi][ni], 0, 0, 0);
    __builtin_amdgcn_s_setprio(0);
  };

  // one phase: t literal, c runtime. p = 9c + t; A bufs by parity of p.
#define PH(t, LASTC) do {                                                          \
    if ((t) == 1 && !(LASTC)) { VMW(4); } else { VMW(0); }                         \
    __builtin_amdgcn_s_barrier();                                                  \
    {                                                                              \
      const int pn = c * 9 + (t) + 1;                                              \
      if (pn < 72) stageA(pn & 1, pn / 9, pn % 9);                                 \
      if ((t) == 0 && !(LASTC)) stageB((c + 1) & 1, c + 1);                        \
    }                                                                              \
    compute((c * 9 + (t)) & 1, c & 1, (t) / 3, (t) % 3);                           \
  } while (0)

  // prologue: B chunk0 first, then A tile0 (so younger-than-A@0 == 0 -> VMW(0))
  stageB(0, 0);
  stageA(0, 0, 0);

#pragma unroll 1
  for (int c = 0; c < 7; ++c) {
    PH(0, 0); PH(1, 0); PH(2, 0); PH(3, 0); PH(4, 0);
    PH(5, 0); PH(6, 0); PH(7, 0); PH(8, 0);
  }
  {
    const int c = 7;
    PH(0, 1); PH(1, 1); PH(2, 1); PH(3, 1); PH(4, 1);
    PH(5, 1); PH(6, 1); PH(7, 1); PH(8, 1);
  }
#undef PH

  // C/D layout: col(pixel) = lane&15, row(co) = (lane>>4)*4 + reg
  if (EPI == 0) {
#pragma unroll
    for (int mi = 0; mi < 4; ++mi) {
      const int co_b = co0 + wm * 64 + mi * 16 + ((lane >> 4) << 2);
      const float s0 = prm[co_b], s1 = prm[co_b + 1], s2 = prm[co_b + 2], s3 = prm[co_b + 3];
      const float t0 = prm[256 + co_b], t1 = prm[256 + co_b + 1],
                  t2 = prm[256 + co_b + 2], t3 = prm[256 + co_b + 3];
#pragma unroll
      for (int ni = 0; ni < 4; ++ni) {
        f32x4 v = acc[mi][ni];
        const int p  = (wn << 6) + (ni << 4) + l15;
        const int pr = p >> 5, pc = p & 31;
        bf16x4 pk;
        pk[0] = (bf16_t)fmaxf(v[0] * s0 + t0, 0.f);
        pk[1] = (bf16_t)fmaxf(v[1] * s1 + t1, 0.f);
        pk[2] = (bf16_t)fmaxf(v[2] * s2 + t2, 0.f);
        pk[3] = (bf16_t)fmaxf(v[3] * s3 + t3, 0.f);
        *(bf16x4*)&out_cl[(n * PLANE + (hb + pr + 1) * HP + pc + 1) * CCH + co_b] = pk;
      }
    }
  } else {
#pragma unroll
    for (int mi = 0; mi < 4; ++mi) {
      const int co_b = co0 + wm * 64 + mi * 16 + ((lane >> 4) << 2);
#pragma unroll
      for (int ni = 0; ni < 4; ++ni) {
        f32x4 v = acc[mi][ni];
        const int p  = (wn << 6) + (ni << 4) + l15;
        const int gp = ((n * CCH + co_b) << 10) + (hb << 5) + p;
        out_f[gp]        = v[0] + resid[gp];
        out_f[gp + 1024] = v[1] + resid[gp + 1024];
        out_f[gp + 2048] = v[2] + resid[gp + 2048];
        out_f[gp + 3072] = v[3] + resid[gp + 3072];
      }
    }
  }
}

extern "C" void kernel_launch(void* const* d_in, const int* in_sizes, int n_in,
                              void* d_out, int out_size, void* d_ws, size_t ws_size,
                              hipStream_t stream) {
  const float* x  = (const float*)d_in[0];
  const float* g1 = (const float*)d_in[1];
  const float* b1 = (const float*)d_in[2];
  const float* m1 = (const float*)d_in[3];
  const float* v1 = (const float*)d_in[4];
  const float* w1 = (const float*)d_in[5];
  const float* k1 = (const float*)d_in[6];
  const float* g2 = (const float*)d_in[7];
  const float* b2 = (const float*)d_in[8];
  const float* m2 = (const float*)d_in[9];
  const float* v2 = (const float*)d_in[10];
  const float* w2 = (const float*)d_in[11];
  const float* k2 = (const float*)d_in[12];

  char* ws = (char*)d_ws;
  const size_t T0P_B = (size_t)64 * PLANE * CCH * 2;
  bf16_t* t0p = (bf16_t*)ws;
  bf16_t* t1p = (bf16_t*)(ws + T0P_B);
  bf16_t* mw1 = (bf16_t*)(ws + 2 * T0P_B);
  bf16_t* mw2 = (bf16_t*)(ws + 2 * T0P_B + 1179648);
  float*  prm = (float*)(ws + 2 * T0P_B + 2 * 1179648);

  prep_params_k<<<1, 256, 0, stream>>>(g1, b1, m1, v1, g2, b2, m2, v2, prm);
  zero_borders_k<<<128, 256, 0, stream>>>(t0p, t1p);
  prep_weights_k<<<256, 256, 0, stream>>>(w1, k1, mw1);
  prep_weights_k<<<256, 256, 0, stream>>>(w2, k2, mw2);
  prep_input_k<<<1024, 256, 0, stream>>>(x, prm, t0p);

  conv3x3_k<0><<<1024, 256, 0, stream>>>(t0p, mw1, prm + 512, nullptr, t1p, nullptr);
  conv3x3_k<1><<<1024, 256, 0, stream>>>(t1p, mw2, nullptr, x, nullptr, (float*)d_out);
}

// Round 10
// 222.498 us; speedup vs baseline: 1.7075x; 1.0134x over previous
//
#include <hip/hip_runtime.h>
#include <hip/hip_bf16.h>
#include <stdint.h>

typedef __bf16 bf16_t;
typedef __bf16 bf16x8 __attribute__((ext_vector_type(8)));
typedef __bf16 bf16x4 __attribute__((ext_vector_type(4)));
typedef float  f32x4  __attribute__((ext_vector_type(4)));
typedef float  f32x16 __attribute__((ext_vector_type(16)));

#define AS_GLOBAL __attribute__((address_space(1)))
#define AS_LDS    __attribute__((address_space(3)))
#define VMW(N) asm volatile("s_waitcnt vmcnt(" #N ")" ::: "memory")

static constexpr int CCH   = 256;
static constexpr int HP    = 34;
static constexpr int PLANE = HP * HP;   // 1156 padded pixels per image

// ---------------- BN parameter folding ----------------
__global__ void prep_params_k(const float* g1, const float* b1, const float* m1, const float* v1,
                              const float* g2, const float* b2, const float* m2, const float* v2,
                              float* prm) {
  int i = threadIdx.x;
  float i1 = g1[i] * rsqrtf(v1[i] + 1e-5f);
  prm[i]       = i1;
  prm[256 + i] = b1[i] - m1[i] * i1;
  float i2 = g2[i] * rsqrtf(v2[i] + 1e-5f);
  prm[512 + i] = i2;
  prm[768 + i] = b2[i] - m2[i] * i2;
}

// ---------------- masked weights -> bf16, [khw][co][ci] ----------------
__global__ __launch_bounds__(256) void prep_weights_k(const float* __restrict__ w,
                                                      const float* __restrict__ msk,
                                                      bf16_t* __restrict__ out) {
  int idx = blockIdx.x * 256 + threadIdx.x;
  const float* wp = w + (long)idx * 9;
  const float* mp = msk + (long)idx * 9;
#pragma unroll
  for (int khw = 0; khw < 9; ++khw)
    out[khw * 65536 + idx] = (bf16_t)(wp[khw] * mp[khw]);
}

// ---------------- zero only the pad borders of both intermediates ----------------
__global__ __launch_bounds__(256) void zero_borders_k(bf16_t* __restrict__ t0p,
                                                      bf16_t* __restrict__ t1p) {
  const int bid = blockIdx.x;               // 128: image n = bid>>1, buffer = bid&1
  bf16_t* base = ((bid & 1) ? t1p : t0p) + (long)(bid >> 1) * PLANE * CCH;
  for (int i = threadIdx.x; i < 132 * 32; i += 256) {
    int pix = i >> 5, c16 = i & 31;
    int r, col;
    if (pix < 34)       { r = 0;           col = pix; }
    else if (pix < 68)  { r = 33;          col = pix - 34; }
    else if (pix < 100) { r = pix - 68 + 1; col = 0; }
    else                { r = pix - 100 + 1; col = 33; }
    *(f32x4*)&base[(r * HP + col) * CCH + c16 * 8] = f32x4{0.f, 0.f, 0.f, 0.f};
  }
}

// ------- relu(bn1(x)) -> bf16, NCHW -> channels-last padded [n][34*34][256] -------
__global__ __launch_bounds__(256) void prep_input_k(const float* __restrict__ x,
                                                    const float* __restrict__ prm,
                                                    bf16_t* __restrict__ t0p) {
  __shared__ __align__(16) bf16_t tile[64 * 256];
  const int tid = threadIdx.x;
  const int bid = blockIdx.x;
  const int n   = bid >> 4;
  const int p0  = (bid & 15) << 6;
  const int px    = tid & 63;
  const int cbase = tid >> 6;
  for (int r = 0; r < 64; ++r) {
    int ci = r * 4 + cbase;
    float v = x[((n * 256 + ci) << 10) + p0 + px];
    float y = fmaxf(v * prm[ci] + prm[256 + ci], 0.f);
    int byte = px * 512 + ((ci * 2) ^ ((px & 7) << 4));
    *(bf16_t*)((char*)tile + byte) = (bf16_t)y;
  }
  __syncthreads();
  for (int j = 0; j < 8; ++j) {
    int off  = j * 256 + tid;
    int pix  = off >> 5;
    int c16  = off & 31;
    int byte = pix * 512 + ((c16 * 16) ^ ((pix & 7) << 4));
    bf16x8 v = *(const bf16x8*)((char*)tile + byte);
    int p = p0 + pix;
    long gp = ((long)n * PLANE + ((p >> 5) + 1) * HP + (p & 31) + 1) * CCH + c16 * 8;
    *(bf16x8*)(t0p + gp) = v;
  }
}

// ---- implicit-GEMM 3x3 conv: A direct global->VGPR, B plane-major LDS, 32x32 ----
// Block 128co x 256px (8r x 32c), 4 waves (wm 2 x wn 2), wave 64co x 128px =
// 2x4 tiles of 32x32, acc f32x16[2][4]. K = 8 ci-chunks x 9 taps x K32.
// A-frags: global->VGPR (L2-hot, 1.2 MB weights), dbuf across taps, NO LDS.
// B: LDS patch per ci-chunk [plane g=2ks+k5][10r][34c] granules -> 32-lane reads
// are 512 B contiguous (bank-optimal, no swizzle). Barrier ONLY at chunk
// boundary (B dbuf swap); waves drift across taps -> natural MFMA/LDS overlap.
template <int EPI>
__global__ __launch_bounds__(256, 2) void conv3x3_k(const bf16_t* __restrict__ inp,
                                                    const bf16_t* __restrict__ wts,
                                                    const float* __restrict__ prm,
                                                    const float* __restrict__ resid,
                                                    bf16_t* __restrict__ out_cl,
                                                    float* __restrict__ out_f) {
  __shared__ __align__(128) bf16_t Bs[2][12288];  // 2 x 24 KB (1360 real + 176 pad granules)

  const int tid  = threadIdx.x;
  const int lane = tid & 63;
  const int wid  = tid >> 6;     // 0..3
  const int wm   = wid >> 1;     // co half of 128 (64 each)
  const int wn   = wid & 1;      // px half (4 rows each)

  const int bid = blockIdx.x;    // 512 = 8 XCD x 64
  const int w   = ((bid & 7) << 6) + (bid >> 3);
  const int co0 = (w & 1) << 7;
  const int pt  = w >> 1;        // 256 px tiles
  const int n   = pt >> 2;
  const int hb  = (pt & 3) << 3; // padded top row of the 10-row patch

  const int l31 = lane & 31;
  const int k5  = lane >> 5;

  // A-frag global base (elems): row = co0 + wm*64 + l31 (+mi*32), k-part = k5*8 (+ks*16)
  const long aBase = (long)(co0 + wm * 64 + l31) * CCH + k5 * 8;
  // B-frag LDS base (elems): plane k5 (+ks*2), row wn*4 (+nj+KH), col pc (+KW)
  const int  bBase = k5 * 2720 + wn * 1088 + l31 * 8;

  // B staging source offsets (granule idx -> (g,r,cc)), piece j covers j*256+tid
  int bofs[6];
#pragma unroll
  for (int j = 0; j < 6; ++j) {
    int idx = j * 256 + tid;
    if (idx > 1359) idx = 1359;                  // source clamp; dest tail -> pad
    const int g   = idx / 340;
    const int rem = idx - g * 340;
    const int r   = rem / 34;
    const int cc  = rem - r * 34;
    bofs[j] = (n * PLANE + (hb + r) * HP + cc) * CCH + g * 8;
  }

  f32x16 acc[2][4];
#pragma unroll
  for (int i = 0; i < 2; ++i)
#pragma unroll
    for (int j = 0; j < 4; ++j)
#pragma unroll
      for (int e = 0; e < 16; ++e) acc[i][j][e] = 0.f;

  bf16x8 avA[4], avB[4], bv[8];

#define STB(BBUF, CI0N, J) do {                                                      \
    const bf16_t* gb_ = inp + bofs[J] + (CI0N);                                      \
    __builtin_amdgcn_global_load_lds((const AS_GLOBAL void*)gb_,                     \
        (AS_LDS void*)(&Bs[BBUF][((J) * 256 + tid) * 8]), 16, 0, 0);                 \
  } while (0)

#define APREF(SET, CI0N, TT) do {                                                    \
    _Pragma("unroll") for (int mi = 0; mi < 2; ++mi)                                 \
    _Pragma("unroll") for (int ks = 0; ks < 2; ++ks)                                 \
      SET[mi * 2 + ks] = *(const bf16x8*)(wts + (long)(TT) * 65536 + aBase           \
                                          + mi * 8192 + (CI0N) + ks * 16);           \
  } while (0)

#define MFMA16(SET) do {                                                             \
    _Pragma("unroll") for (int mi = 0; mi < 2; ++mi)                                 \
    _Pragma("unroll") for (int nj = 0; nj < 4; ++nj)                                 \
    _Pragma("unroll") for (int ks = 0; ks < 2; ++ks)                                 \
      acc[mi][nj] = __builtin_amdgcn_mfma_f32_32x32x16_bf16(                         \
          SET[mi * 2 + ks], bv[nj * 2 + ks], acc[mi][nj], 0, 0, 0);                  \
  } while (0)

  // one tap. T/PAR/LASTC literal, c runtime. A-set used = (PAR+T)&1 ? avB : avA.
#define TAPB(T, PAR, LASTC) do {                                                     \
    constexpr int KH = (T) / 3, KW = (T) % 3;                                        \
    _Pragma("unroll") for (int nj = 0; nj < 4; ++nj)                                 \
    _Pragma("unroll") for (int ks = 0; ks < 2; ++ks)                                 \
      bv[nj * 2 + ks] = *(const bf16x8*)&bsrd[bBase + ks * 5440                      \
                                              + (nj + KH) * 272 + KW * 8];           \
    if (!(LASTC) && (T) <= 5) STB((c + 1) & 1, (c + 1) << 5, T);                     \
    if (!((LASTC) && (T) == 8)) {                                                    \
      constexpr int TN = ((T) + 1) % 9;                                              \
      const int cin = ((T) == 8) ? ((c + 1) << 5) : (c << 5);                        \
      if (((PAR) + (T)) & 1) { APREF(avA, cin, TN); } else { APREF(avB, cin, TN); }  \
    }                                                                                \
    __builtin_amdgcn_s_setprio(1);                                                   \
    if (((PAR) + (T)) & 1) { MFMA16(avB); } else { MFMA16(avA); }                    \
    __builtin_amdgcn_s_setprio(0);                                                   \
  } while (0)

#define CHUNKB(PAR, LASTC) do {                                                      \
    const bf16_t* bsrd = &Bs[c & 1][0];                                              \
    TAPB(0, PAR, LASTC); TAPB(1, PAR, LASTC); TAPB(2, PAR, LASTC);                   \
    TAPB(3, PAR, LASTC); TAPB(4, PAR, LASTC); TAPB(5, PAR, LASTC);                   \
    TAPB(6, PAR, LASTC); TAPB(7, PAR, LASTC); TAPB(8, PAR, LASTC);                   \
    if (!(LASTC)) { VMW(0); __builtin_amdgcn_s_barrier(); }                          \
  } while (0)

  // prologue: B(chunk0) all 6 pieces; A(tap0) into set A; drain; barrier
  STB(0, 0, 0); STB(0, 0, 1); STB(0, 0, 2); STB(0, 0, 3); STB(0, 0, 4); STB(0, 0, 5);
  APREF(avA, 0, 0);
  VMW(0);
  __builtin_amdgcn_s_barrier();

  int c = 0;
#pragma unroll 1
  for (int it = 0; it < 3; ++it) {
    CHUNKB(0, 0); ++c;
    CHUNKB(1, 0); ++c;
  }
  CHUNKB(0, 0); ++c;          // c = 6
  CHUNKB(1, 1);               // c = 7 tail

#undef TAPB
#undef CHUNKB
#undef APREF
#undef MFMA16
#undef STB

  // C/D 32x32 layout: col = lane&31, row = (reg&3) + 8*(reg>>2) + 4*(lane>>5)
  if (EPI == 0) {
#pragma unroll
    for (int mi = 0; mi < 2; ++mi)
#pragma unroll
      for (int nj = 0; nj < 4; ++nj) {
        const int prow = hb + wn * 4 + nj;              // unpadded px row
        const long pbase = ((long)n * PLANE + (prow + 1) * HP + l31 + 1) * CCH;
#pragma unroll
        for (int q = 0; q < 4; ++q) {
          const int co_b = co0 + wm * 64 + mi * 32 + q * 8 + k5 * 4;
          const float s0 = prm[co_b], s1 = prm[co_b + 1], s2 = prm[co_b + 2], s3 = prm[co_b + 3];
          const float t0 = prm[256 + co_b], t1 = prm[256 + co_b + 1],
                      t2 = prm[256 + co_b + 2], t3 = prm[256 + co_b + 3];
          bf16x4 pk;
          pk[0] = (bf16_t)fmaxf(acc[mi][nj][q * 4 + 0] * s0 + t0, 0.f);
          pk[1] = (bf16_t)fmaxf(acc[mi][nj][q * 4 + 1] * s1 + t1, 0.f);
          pk[2] = (bf16_t)fmaxf(acc[mi][nj][q * 4 + 2] * s2 + t2, 0.f);
          pk[3] = (bf16_t)fmaxf(acc[mi][nj][q * 4 + 3] * s3 + t3, 0.f);
          *(bf16x4*)&out_cl[pbase + co_b] = pk;
        }
      }
  } else {
#pragma unroll
    for (int mi = 0; mi < 2; ++mi)
#pragma unroll
      for (int nj = 0; nj < 4; ++nj) {
        const int prow = hb + wn * 4 + nj;
        const int ppos = prow * 32 + l31;
#pragma unroll
        for (int q = 0; q < 4; ++q) {
          const int co_b = co0 + wm * 64 + mi * 32 + q * 8 + k5 * 4;
#pragma unroll
          for (int e = 0; e < 4; ++e) {
            const long gp = (((long)n * CCH + co_b + e) << 10) + ppos;
            out_f[gp] = acc[mi][nj][q * 4 + e] + resid[gp];
          }
        }
      }
  }
}

extern "C" void kernel_launch(void* const* d_in, const int* in_sizes, int n_in,
                              void* d_out, int out_size, void* d_ws, size_t ws_size,
                              hipStream_t stream) {
  const float* x  = (const float*)d_in[0];
  const float* g1 = (const float*)d_in[1];
  const float* b1 = (const float*)d_in[2];
  const float* m1 = (const float*)d_in[3];
  const float* v1 = (const float*)d_in[4];
  const float* w1 = (const float*)d_in[5];
  const float* k1 = (const float*)d_in[6];
  const float* g2 = (const float*)d_in[7];
  const float* b2 = (const float*)d_in[8];
  const float* m2 = (const float*)d_in[9];
  const float* v2 = (const float*)d_in[10];
  const float* w2 = (const float*)d_in[11];
  const float* k2 = (const float*)d_in[12];

  char* ws = (char*)d_ws;
  const size_t T0P_B = (size_t)64 * PLANE * CCH * 2;
  bf16_t* t0p = (bf16_t*)ws;
  bf16_t* t1p = (bf16_t*)(ws + T0P_B);
  bf16_t* mw1 = (bf16_t*)(ws + 2 * T0P_B);
  bf16_t* mw2 = (bf16_t*)(ws + 2 * T0P_B + 1179648);
  float*  prm = (float*)(ws + 2 * T0P_B + 2 * 1179648);

  prep_params_k<<<1, 256, 0, stream>>>(g1, b1, m1, v1, g2, b2, m2, v2, prm);
  zero_borders_k<<<128, 256, 0, stream>>>(t0p, t1p);
  prep_weights_k<<<256, 256, 0, stream>>>(w1, k1, mw1);
  prep_weights_k<<<256, 256, 0, stream>>>(w2, k2, mw2);
  prep_input_k<<<1024, 256, 0, stream>>>(x, prm, t0p);

  conv3x3_k<0><<<512, 256, 0, stream>>>(t0p, mw1, prm + 512, nullptr, t1p, nullptr);
  conv3x3_k<1><<<512, 256, 0, stream>>>(t1p, mw2, nullptr, x, nullptr, (float*)d_out);
}